// Round 5
// baseline (174.191 us; speedup 1.0000x reference)
//
#include <hip/hip_runtime.h>

#define N_ATOMS 4096
#define CUTOFF 0.5f
#define CHUNK 4      // pairs per thread, at stride blockDim (keeps stores coalesced)
#define TPB 256

typedef float f32x4 __attribute__((ext_vector_type(4)));

__global__ __launch_bounds__(TPB) void nbr_kernel(
    const float* __restrict__ pos,
    const float* __restrict__ box,
    f32x4* __restrict__ out,
    int n_pairs)
{
    // orthogonal box: diagonal of box_vectors
    const float Lx = box[0], Ly = box[4], Lz = box[8];
    const float hx = 0.5f * Lx, hy = 0.5f * Ly, hz = 0.5f * Lz;

    int p = blockIdx.x * (TPB * CHUNK) + threadIdx.x;
    if (p >= n_pairs) return;

    // --- Analytic inversion p -> (i, r=row_start(i)), once per thread. ---
    // i ~ floor(((2N-1) - sqrt((2N-1)^2 - 8p)) / 2); integer fixup loops make
    // it exact (f32 sqrt of D<=6.7e7 can be off by ~1 in the guess).
    unsigned D = (2u * N_ATOMS - 1) * (2u * N_ATOMS - 1) - 8u * (unsigned)p;
    float t = sqrtf((float)D);
    int i = (int)(((float)(2 * N_ATOMS - 1) - t) * 0.5f);
    i = max(0, min(i, N_ATOMS - 2));
    int r = i * (N_ATOMS - 1) - (i * (i - 1)) / 2;   // row_start(i)
    while (r > p)                          { r -= (N_ATOMS - i); --i; }     // len(i-1) = N-i
    while (p >= r + (N_ATOMS - 1 - i))     { r += (N_ATOMS - 1 - i); ++i; } // len(i)   = N-1-i

    float xi = pos[3 * i], yi = pos[3 * i + 1], zi = pos[3 * i + 2];

    #pragma unroll
    for (int c = 0; c < CHUNK; ++c) {
        if (p < n_pairs) {
            const int j = p - r + i + 1;
            const float xj = pos[3 * j], yj = pos[3 * j + 1], zj = pos[3 * j + 2];

            // Range-bounded periodic wrap, bit-identical to
            // jnp.remainder(r + half, L) - half for r in (-L, L).
            float tx = (xi - xj) + hx;
            tx = (tx >= Lx) ? tx - Lx : tx;
            tx = (tx <  0.0f) ? tx + Lx : tx;
            const float wx = tx - hx;

            float ty = (yi - yj) + hy;
            ty = (ty >= Ly) ? ty - Ly : ty;
            ty = (ty <  0.0f) ? ty + Ly : ty;
            const float wy = ty - hy;

            float tz = (zi - zj) + hz;
            tz = (tz >= Lz) ? tz - Lz : tz;
            tz = (tz <  0.0f) ? tz + Lz : tz;
            const float wz = tz - hz;

            const float d = sqrtf(wx * wx + wy * wy + wz * wz);
            const float m = (d <= CUTOFF) ? 1.0f : 0.0f;

            f32x4 v;
            v.x = wx * m; v.y = wy * m; v.z = wz * m; v.w = d * m;
            // lane-consecutive 16B -> 1KB/wave, nontemporal (no reuse)
            __builtin_nontemporal_store(v, &out[p]);
        }

        // advance to p + TPB: incremental (i, row_start) update, no sqrt.
        p += TPB;
        if (c + 1 < CHUNK && p < n_pairs) {
            const int iprev = i;
            while (p >= r + (N_ATOMS - 1 - i)) { r += (N_ATOMS - 1 - i); ++i; }
            if (i != iprev) {
                xi = pos[3 * i]; yi = pos[3 * i + 1]; zi = pos[3 * i + 2];
            }
        }
    }
}

extern "C" void kernel_launch(void* const* d_in, const int* in_sizes, int n_in,
                              void* d_out, int out_size, void* d_ws, size_t ws_size,
                              hipStream_t stream) {
    const float* pos = (const float*)d_in[0];   // [4096, 3] f32
    const float* box = (const float*)d_in[1];   // [3, 3] f32
    // d_in[2]/d_in[3] (i_pairs/j_pairs) intentionally unread: triu order is
    // reconstructed analytically, saving 67 MB of HBM reads.
    const int n_pairs = in_sizes[2];

    f32x4* out = (f32x4*)d_out;                 // [n_pairs, 4] f32

    const int pairs_per_block = TPB * CHUNK;
    const int blocks = (n_pairs + pairs_per_block - 1) / pairs_per_block;

    nbr_kernel<<<blocks, TPB, 0, stream>>>(pos, box, out, n_pairs);
}